// Round 1
// baseline (431.773 us; speedup 1.0000x reference)
//
#include <hip/hip_runtime.h>
#include <stdint.h>

#define EMB 1024
#define NHEAD 16
#define DH 64
#define SEQ 2048
#define NTOK 4096   // B*N

typedef __attribute__((ext_vector_type(8))) short s16x8;
typedef __attribute__((ext_vector_type(4))) float f32x4;
typedef __attribute__((ext_vector_type(4))) unsigned short u16x4;

__device__ __forceinline__ unsigned short f2bf(float f){
    union { float f; unsigned int u; } v; v.f = f;
    unsigned int r = v.u + 0x7fffu + ((v.u >> 16) & 1u);
    return (unsigned short)(r >> 16);
}

__device__ __forceinline__ f32x4 mfma16(s16x8 a, s16x8 b, f32x4 c){
    return __builtin_amdgcn_mfma_f32_16x16x32_bf16(a, b, c, 0, 0, 0);
}

// ---------------- transpose + fp32->bf16 convert: out[C][R] = bf16(in[R][C]) ----------------
__global__ __launch_bounds__(256) void convT_kernel(const float* __restrict__ in,
                                                    unsigned short* __restrict__ out,
                                                    int R, int C){
    __shared__ float tile[32][33];
    const int c0 = blockIdx.x * 32, r0 = blockIdx.y * 32;
    const int tx = threadIdx.x, ty = threadIdx.y;   // 32 x 8
    #pragma unroll
    for (int k = 0; k < 4; ++k)
        tile[ty*4+k][tx] = in[(long)(r0 + ty*4 + k) * C + c0 + tx];
    __syncthreads();
    #pragma unroll
    for (int k = 0; k < 4; ++k)
        out[(long)(c0 + ty*4 + k) * R + r0 + tx] = f2bf(tile[tx][ty*4+k]);
}

// ---------------- LayerNorm (1024 cols) fp32 in -> bf16 out ----------------
__global__ __launch_bounds__(256) void ln_kernel(const float* __restrict__ x,
                                                 const float* __restrict__ w,
                                                 const float* __restrict__ b,
                                                 unsigned short* __restrict__ out){
    const int row = blockIdx.x, tid = threadIdx.x;
    const float4 v = ((const float4*)(x + (long)row * EMB))[tid];
    float s  = v.x + v.y + v.z + v.w;
    float ss = v.x*v.x + v.y*v.y + v.z*v.z + v.w*v.w;
    #pragma unroll
    for (int off = 32; off >= 1; off >>= 1){
        s  += __shfl_xor(s,  off, 64);
        ss += __shfl_xor(ss, off, 64);
    }
    __shared__ float ps[4], pss[4];
    const int wv = tid >> 6;
    if ((tid & 63) == 0){ ps[wv] = s; pss[wv] = ss; }
    __syncthreads();
    s  = ps[0] + ps[1] + ps[2] + ps[3];
    ss = pss[0] + pss[1] + pss[2] + pss[3];
    const float mean = s * (1.0f/EMB);
    const float var  = ss * (1.0f/EMB) - mean*mean;
    const float rstd = rsqrtf(var + 1e-5f);
    const float4 wv4 = ((const float4*)w)[tid];
    const float4 bv4 = ((const float4*)b)[tid];
    u16x4 o;
    o[0] = f2bf((v.x - mean) * rstd * wv4.x + bv4.x);
    o[1] = f2bf((v.y - mean) * rstd * wv4.y + bv4.y);
    o[2] = f2bf((v.z - mean) * rstd * wv4.z + bv4.z);
    o[3] = f2bf((v.w - mean) * rstd * wv4.w + bv4.w);
    *(u16x4*)(out + (long)row * EMB + tid * 4) = o;
}

// ---------------- GEMM: C[M][N] = A[M][K] * Bt[N][K]^T  (bf16 in, fp32 acc) ----------------
// EPI 0: bf16 out plain; 1: fp32 out + bias + resid; 2: bf16 out + bias + gelu(tanh)
template<int EPI, int BM, int BN>
__global__ __launch_bounds__(256) void gemm_kernel(const unsigned short* __restrict__ A,
                                                   const unsigned short* __restrict__ Bt,
                                                   const float* __restrict__ bias,
                                                   const float* __restrict__ resid,
                                                   void* __restrict__ outv,
                                                   int M, int N, int K){
    constexpr int FI = BM / 32;           // frags per wave in M
    constexpr int FJ = BN / 32;           // frags per wave in N
    __shared__ unsigned short As[BM * 32];
    __shared__ unsigned short Bs[BN * 32];
    const int tid  = threadIdx.x;
    const int lane = tid & 63, wv = tid >> 6;
    const int lm = lane & 15, g = lane >> 4;
    const int wr = wv >> 1, wc = wv & 1;
    const int m0 = blockIdx.y * BM, n0 = blockIdx.x * BN;
    const int r_st = tid >> 2, q_st = (tid & 3) * 8;

    f32x4 zero = {0.0f, 0.0f, 0.0f, 0.0f};
    f32x4 acc[FI][FJ];
    #pragma unroll
    for (int i = 0; i < FI; ++i)
        #pragma unroll
        for (int j = 0; j < FJ; ++j) acc[i][j] = zero;

    for (int kt = 0; kt < K; kt += 32){
        __syncthreads();
        #pragma unroll
        for (int p = 0; p < BM/64; ++p)
            *(uint4*)&As[(r_st + p*64)*32 + q_st] =
                *(const uint4*)&A[(long)(m0 + r_st + p*64) * K + kt + q_st];
        #pragma unroll
        for (int p = 0; p < BN/64; ++p)
            *(uint4*)&Bs[(r_st + p*64)*32 + q_st] =
                *(const uint4*)&Bt[(long)(n0 + r_st + p*64) * K + kt + q_st];
        __syncthreads();
        s16x8 af[FI], bf[FJ];
        #pragma unroll
        for (int i = 0; i < FI; ++i)
            af[i] = *(const s16x8*)&As[(wr*(BM/2) + i*16 + lm)*32 + g*8];
        #pragma unroll
        for (int j = 0; j < FJ; ++j)
            bf[j] = *(const s16x8*)&Bs[(wc*(BN/2) + j*16 + lm)*32 + g*8];
        #pragma unroll
        for (int i = 0; i < FI; ++i)
            #pragma unroll
            for (int j = 0; j < FJ; ++j)
                acc[i][j] = mfma16(af[i], bf[j], acc[i][j]);
    }

    #pragma unroll
    for (int i = 0; i < FI; ++i){
        #pragma unroll
        for (int r = 0; r < 4; ++r){
            const int row = m0 + wr*(BM/2) + i*16 + 4*g + r;
            #pragma unroll
            for (int j = 0; j < FJ; ++j){
                const int col = n0 + wc*(BN/2) + j*16 + lm;
                const float v = acc[i][j][r];
                if (EPI == 0){
                    ((unsigned short*)outv)[(long)row * N + col] = f2bf(v);
                } else if (EPI == 1){
                    ((float*)outv)[(long)row * N + col] =
                        v + bias[col] + resid[(long)row * N + col];
                } else {
                    const float xx = v + bias[col];
                    const float gg = 0.5f * xx *
                        (1.0f + tanhf(0.7978845608f * (xx + 0.044715f * xx * xx * xx)));
                    ((unsigned short*)outv)[(long)row * N + col] = f2bf(gg);
                }
            }
        }
    }
}

// ---------------- causal flash attention: qkv bf16 [NTOK][3E] -> ctx bf16 [NTOK][E] ----------------
// 1 wave per block; wave owns 16 query rows of one (b,h). Computes S^T = K·Q^T so the
// softmax'd P tile feeds PV directly from the C/D register layout.
__global__ __launch_bounds__(64) void attn_kernel(const unsigned short* __restrict__ qkv,
                                                  unsigned short* __restrict__ ctx){
    const int qt = blockIdx.x, bh = blockIdx.y;
    const int b = bh >> 4, h = bh & 15;
    const int lane = threadIdx.x, lm = lane & 15, g = lane >> 4;
    const int q0 = qt * 16;
    const long base = (long)b * SEQ * (3*EMB);

    const unsigned short* qrow = qkv + base + (long)(q0 + lm)*(3*EMB) + h*DH + g*8;
    const s16x8 qf0 = *(const s16x8*)qrow;
    const s16x8 qf1 = *(const s16x8*)(qrow + 32);

    f32x4 zero = {0.0f, 0.0f, 0.0f, 0.0f};
    f32x4 o[4];
    #pragma unroll
    for (int d = 0; d < 4; ++d) o[d] = zero;
    float mrun = -1e30f, lrun = 0.0f;
    const int qg = q0 + lm;
    const int ntiles = (q0 + 15)/32 + 1;

    for (int t = 0; t < ntiles; ++t){
        const int kv0 = t * 32;
        const unsigned short* krow = qkv + base + (long)(kv0 + lm)*(3*EMB) + EMB + h*DH + g*8;
        const unsigned short* krow2 = krow + 16*(3*EMB);
        f32x4 s0 = zero, s1 = zero;
        s0 = mfma16(*(const s16x8*)krow,       qf0, s0);
        s0 = mfma16(*(const s16x8*)(krow+32),  qf1, s0);
        s1 = mfma16(*(const s16x8*)krow2,      qf0, s1);
        s1 = mfma16(*(const s16x8*)(krow2+32), qf1, s1);

        float p0[4], p1[4];
        float tmax = -1e30f;
        #pragma unroll
        for (int r = 0; r < 4; ++r){
            const int kk0 = kv0 + 4*g + r;
            const float a0 = (kk0      <= qg) ? s0[r]*0.125f : -1e30f;
            const float a1 = (kk0 + 16 <= qg) ? s1[r]*0.125f : -1e30f;
            p0[r] = a0; p1[r] = a1;
            tmax = fmaxf(tmax, fmaxf(a0, a1));
        }
        tmax = fmaxf(tmax, __shfl_xor(tmax, 16, 64));
        tmax = fmaxf(tmax, __shfl_xor(tmax, 32, 64));
        const float mnew = fmaxf(mrun, tmax);
        const float corr = __expf(mrun - mnew);
        float rsum = 0.0f;
        s16x8 pf;
        #pragma unroll
        for (int r = 0; r < 4; ++r){
            const float e0 = __expf(p0[r] - mnew);
            const float e1 = __expf(p1[r] - mnew);
            rsum += e0 + e1;
            pf[r]   = (short)f2bf(e0);
            pf[r+4] = (short)f2bf(e1);
        }
        rsum += __shfl_xor(rsum, 16, 64);
        rsum += __shfl_xor(rsum, 32, 64);
        lrun = lrun * corr + rsum;
        mrun = mnew;
        #pragma unroll
        for (int d = 0; d < 4; ++d){
            o[d][0] *= corr; o[d][1] *= corr; o[d][2] *= corr; o[d][3] *= corr;
        }
        const unsigned short* vbase = qkv + base + (long)kv0*(3*EMB) + 2*EMB + h*DH;
        #pragma unroll
        for (int d = 0; d < 4; ++d){
            s16x8 vf;
            #pragma unroll
            for (int e = 0; e < 8; ++e){
                const int kk = 4*g + (e & 3) + ((e >> 2) << 4);
                vf[e] = (short)vbase[(long)kk*(3*EMB) + d*16 + lm];
            }
            o[d] = mfma16(vf, pf, o[d]);
        }
    }

    const float inv = 1.0f / lrun;
    unsigned short* crow = ctx + (long)(b*SEQ + q0 + lm)*EMB + h*DH + g*4;
    #pragma unroll
    for (int d = 0; d < 4; ++d){
        u16x4 ov;
        ov[0] = f2bf(o[d][0]*inv); ov[1] = f2bf(o[d][1]*inv);
        ov[2] = f2bf(o[d][2]*inv); ov[3] = f2bf(o[d][3]*inv);
        *(u16x4*)(crow + d*16) = ov;
    }
}

// ---------------- launch ----------------
extern "C" void kernel_launch(void* const* d_in, const int* in_sizes, int n_in,
                              void* d_out, int out_size, void* d_ws, size_t ws_size,
                              hipStream_t stream){
    const float* x     = (const float*)d_in[0];
    const float* ln1_w = (const float*)d_in[1];
    const float* ln1_b = (const float*)d_in[2];
    const float* w_qkv = (const float*)d_in[3];
    const float* w_ap  = (const float*)d_in[4];
    const float* b_ap  = (const float*)d_in[5];
    const float* ln2_w = (const float*)d_in[6];
    const float* ln2_b = (const float*)d_in[7];
    const float* w_fc  = (const float*)d_in[8];
    const float* b_fc  = (const float*)d_in[9];
    const float* w_pr  = (const float*)d_in[10];
    const float* b_pr  = (const float*)d_in[11];
    float* out = (float*)d_out;

    char* ws = (char*)d_ws;
    unsigned short* wqkvT = (unsigned short*)(ws + 0);          // [3072][1024]
    unsigned short* wapT  = (unsigned short*)(ws + 6291456);    // [1024][1024]
    unsigned short* wfcT  = (unsigned short*)(ws + 8388608);    // [4096][1024]
    unsigned short* wprT  = (unsigned short*)(ws + 16777216);   // [1024][4096]
    unsigned short* h1    = (unsigned short*)(ws + 25165824);   // [4096][1024]
    unsigned short* qkv   = (unsigned short*)(ws + 33554432);   // [4096][3072]
    unsigned short* ctx   = (unsigned short*)(ws + 58720256);   // [4096][1024]
    float*          x1    = (float*)(ws + 67108864);            // [4096][1024]
    unsigned short* h2    = (unsigned short*)(ws + 83886080);   // [4096][1024]
    unsigned short* afc   = (unsigned short*)(ws + 92274688);   // [4096][4096]
    // total ws use: 125829120 bytes

    dim3 b32(32, 8, 1);
    convT_kernel<<<dim3(3072/32, 1024/32), b32, 0, stream>>>(w_qkv, wqkvT, 1024, 3072);
    convT_kernel<<<dim3(1024/32, 1024/32), b32, 0, stream>>>(w_ap,  wapT,  1024, 1024);
    convT_kernel<<<dim3(4096/32, 1024/32), b32, 0, stream>>>(w_fc,  wfcT,  1024, 4096);
    convT_kernel<<<dim3(1024/32, 4096/32), b32, 0, stream>>>(w_pr,  wprT,  4096, 1024);

    ln_kernel<<<NTOK, 256, 0, stream>>>(x, ln1_w, ln1_b, h1);

    gemm_kernel<0,128,128><<<dim3(3072/128, NTOK/128), 256, 0, stream>>>(
        h1, wqkvT, nullptr, nullptr, qkv, NTOK, 3072, 1024);

    attn_kernel<<<dim3(SEQ/16, 32), 64, 0, stream>>>(qkv, ctx);

    gemm_kernel<1,128,64><<<dim3(1024/64, NTOK/128), 256, 0, stream>>>(
        ctx, wapT, b_ap, x, x1, NTOK, 1024, 1024);

    ln_kernel<<<NTOK, 256, 0, stream>>>(x1, ln2_w, ln2_b, h2);

    gemm_kernel<2,128,128><<<dim3(4096/128, NTOK/128), 256, 0, stream>>>(
        h2, wfcT, b_fc, nullptr, afc, NTOK, 4096, 1024);

    gemm_kernel<1,128,64><<<dim3(1024/64, NTOK/128), 256, 0, stream>>>(
        afc, wprT, b_pr, x1, out, NTOK, 1024, 4096);
}

// Round 2
// 285.999 us; speedup vs baseline: 1.5097x; 1.5097x over previous
//
#include <hip/hip_runtime.h>
#include <stdint.h>

#define EMB 1024
#define NHEAD 16
#define DH 64
#define SEQ 2048
#define NTOK 4096   // B*N

typedef __attribute__((ext_vector_type(8))) short s16x8;
typedef __attribute__((ext_vector_type(4))) short s16x4;
typedef __attribute__((ext_vector_type(4))) float f32x4;
typedef __attribute__((ext_vector_type(4))) unsigned short u16x4;

__device__ __forceinline__ unsigned short f2bf(float f){
    union { float f; unsigned int u; } v; v.f = f;
    unsigned int r = v.u + 0x7fffu + ((v.u >> 16) & 1u);
    return (unsigned short)(r >> 16);
}

__device__ __forceinline__ f32x4 mfma16(s16x8 a, s16x8 b, f32x4 c){
    return __builtin_amdgcn_mfma_f32_16x16x32_bf16(a, b, c, 0, 0, 0);
}

__device__ __forceinline__ void gload16(const void* g, void* l){
    __builtin_amdgcn_global_load_lds((const __attribute__((address_space(1))) void*)g,
                                     (__attribute__((address_space(3))) void*)l, 16, 0, 0);
}

__device__ __forceinline__ s16x8 cat8(s16x4 a, s16x4 b){
    s16x8 r;
    r[0]=a[0]; r[1]=a[1]; r[2]=a[2]; r[3]=a[3];
    r[4]=b[0]; r[5]=b[1]; r[6]=b[2]; r[7]=b[3];
    return r;
}

// ---------------- transpose + fp32->bf16 convert: out[C][R] = bf16(in[R][C]) ----------------
__global__ __launch_bounds__(256) void convT_kernel(const float* __restrict__ in,
                                                    unsigned short* __restrict__ out,
                                                    int R, int C){
    __shared__ float tile[32][33];
    const int c0 = blockIdx.x * 32, r0 = blockIdx.y * 32;
    const int tx = threadIdx.x, ty = threadIdx.y;   // 32 x 8
    #pragma unroll
    for (int k = 0; k < 4; ++k)
        tile[ty*4+k][tx] = in[(long)(r0 + ty*4 + k) * C + c0 + tx];
    __syncthreads();
    #pragma unroll
    for (int k = 0; k < 4; ++k)
        out[(long)(c0 + ty*4 + k) * R + r0 + tx] = f2bf(tile[tx][ty*4+k]);
}

// ---------------- V-transpose: qkv V-part [tok][3E] -> vtg[bh][64][2048] bf16 ----------------
__global__ __launch_bounds__(256) void vT_kernel(const unsigned short* __restrict__ qkv,
                                                 unsigned short* __restrict__ vtg){
    __shared__ unsigned short tile[64*64];
    const int bh = blockIdx.y, b = bh >> 4, h = bh & 15;
    const int n0 = blockIdx.x * 64;
    const int t = threadIdx.x;
    const int nr = t >> 3, c0 = (t & 7) * 8;
    // tile[n][d] swizzled: byte = n*128 + (d*2 ^ (((n>>3)&7)<<4))
    #pragma unroll
    for (int hh = 0; hh < 2; ++hh){
        const int n = nr + hh*32;
        uint4 vv = *(const uint4*)&qkv[(long)(b*SEQ + n0 + n)*3072 + 2048 + h*64 + c0];
        *(uint4*)((char*)tile + n*128 + ((c0*2) ^ (((n>>3)&7)<<4))) = vv;
    }
    __syncthreads();
    #pragma unroll
    for (int hh = 0; hh < 2; ++hh){
        const int d = nr + hh*32;
        union { unsigned short u[8]; uint4 v; } tmp;
        #pragma unroll
        for (int j = 0; j < 8; ++j){
            const int n = c0 + j;
            tmp.u[j] = *(const unsigned short*)((char*)tile + n*128 + ((d*2) ^ (((n>>3)&7)<<4)));
        }
        *(uint4*)&vtg[((long)bh*64 + d)*2048 + n0 + c0] = tmp.v;
    }
}

// ---------------- LayerNorm (1024 cols) fp32 in -> bf16 out ----------------
__global__ __launch_bounds__(256) void ln_kernel(const float* __restrict__ x,
                                                 const float* __restrict__ w,
                                                 const float* __restrict__ b,
                                                 unsigned short* __restrict__ out){
    const int row = blockIdx.x, tid = threadIdx.x;
    const float4 v = ((const float4*)(x + (long)row * EMB))[tid];
    float s  = v.x + v.y + v.z + v.w;
    float ss = v.x*v.x + v.y*v.y + v.z*v.z + v.w*v.w;
    #pragma unroll
    for (int off = 32; off >= 1; off >>= 1){
        s  += __shfl_xor(s,  off, 64);
        ss += __shfl_xor(ss, off, 64);
    }
    __shared__ float ps[4], pss[4];
    const int wv = tid >> 6;
    if ((tid & 63) == 0){ ps[wv] = s; pss[wv] = ss; }
    __syncthreads();
    s  = ps[0] + ps[1] + ps[2] + ps[3];
    ss = pss[0] + pss[1] + pss[2] + pss[3];
    const float mean = s * (1.0f/EMB);
    const float var  = ss * (1.0f/EMB) - mean*mean;
    const float rstd = rsqrtf(var + 1e-5f);
    const float4 wv4 = ((const float4*)w)[tid];
    const float4 bv4 = ((const float4*)b)[tid];
    u16x4 o;
    o[0] = f2bf((v.x - mean) * rstd * wv4.x + bv4.x);
    o[1] = f2bf((v.y - mean) * rstd * wv4.y + bv4.y);
    o[2] = f2bf((v.z - mean) * rstd * wv4.z + bv4.z);
    o[3] = f2bf((v.w - mean) * rstd * wv4.w + bv4.w);
    *(u16x4*)(out + (long)row * EMB + tid * 4) = o;
}

// ---------------- GEMM: C[M][N] = A[M][K] * Bt[N][K]^T  (bf16 in, fp32 acc) ----------------
// m97 structure: global_load_lds staging, double-buffered LDS, 1 barrier / K-step.
// EPI 0: bf16 out plain; 1: fp32 out + bias + resid; 2: bf16 out + bias + gelu(tanh)
template<int EPI, int BM, int BN>
__global__ __launch_bounds__(256) void gemm_kernel(const unsigned short* __restrict__ A,
                                                   const unsigned short* __restrict__ Bt,
                                                   const float* __restrict__ bias,
                                                   const float* __restrict__ resid,
                                                   void* __restrict__ outv,
                                                   int M, int N, int K){
    constexpr int FI = BM / 32;
    constexpr int FJ = BN / 32;
    __shared__ unsigned short As[2][BM * 32];
    __shared__ unsigned short Bs[2][BN * 32];
    const int tid  = threadIdx.x;
    const int lane = tid & 63, w = tid >> 6;
    const int lm = lane & 15, g = lane >> 4;
    const int wr = w >> 1, wc = w & 1;
    const int m0 = blockIdx.y * BM, n0 = blockIdx.x * BN;
    const int r_st = tid >> 2, q_st = (tid & 3) * 8;

    f32x4 zero = {0.0f, 0.0f, 0.0f, 0.0f};
    f32x4 acc[FI][FJ];
    #pragma unroll
    for (int i = 0; i < FI; ++i)
        #pragma unroll
        for (int j = 0; j < FJ; ++j) acc[i][j] = zero;

    auto stage = [&](int kt, int bu){
        #pragma unroll
        for (int p = 0; p < BM/64; ++p)
            gload16(&A[(long)(m0 + r_st + p*64) * K + kt + q_st],
                    (char*)&As[bu][0] + p*4096 + w*1024);
        #pragma unroll
        for (int p = 0; p < BN/64; ++p)
            gload16(&Bt[(long)(n0 + r_st + p*64) * K + kt + q_st],
                    (char*)&Bs[bu][0] + p*4096 + w*1024);
    };

    stage(0, 0);
    int cur = 0;
    const int nkt = K / 32;
    for (int t = 0; t < nkt; ++t){
        __syncthreads();                      // drains vmcnt: buf[cur] ready, buf[cur^1] free
        if (t + 1 < nkt) stage((t+1)*32, cur ^ 1);
        s16x8 af[FI], bf[FJ];
        #pragma unroll
        for (int i = 0; i < FI; ++i)
            af[i] = *(const s16x8*)&As[cur][(wr*(BM/2) + i*16 + lm)*32 + g*8];
        #pragma unroll
        for (int j = 0; j < FJ; ++j)
            bf[j] = *(const s16x8*)&Bs[cur][(wc*(BN/2) + j*16 + lm)*32 + g*8];
        #pragma unroll
        for (int i = 0; i < FI; ++i)
            #pragma unroll
            for (int j = 0; j < FJ; ++j)
                acc[i][j] = mfma16(af[i], bf[j], acc[i][j]);
        cur ^= 1;
    }

    #pragma unroll
    for (int i = 0; i < FI; ++i){
        #pragma unroll
        for (int r = 0; r < 4; ++r){
            const int row = m0 + wr*(BM/2) + i*16 + 4*g + r;
            #pragma unroll
            for (int j = 0; j < FJ; ++j){
                const int col = n0 + wc*(BN/2) + j*16 + lm;
                const float v = acc[i][j][r];
                if (EPI == 0){
                    ((unsigned short*)outv)[(long)row * N + col] = f2bf(v);
                } else if (EPI == 1){
                    ((float*)outv)[(long)row * N + col] =
                        v + bias[col] + resid[(long)row * N + col];
                } else {
                    const float xx = v + bias[col];
                    const float z = 0.7978845608f * (xx + 0.044715f * xx * xx * xx);
                    const float gg = xx / (1.0f + __expf(-2.0f * z));
                    ((unsigned short*)outv)[(long)row * N + col] = f2bf(gg);
                }
            }
        }
    }
}

// ---------------- causal flash attention ----------------
// 256-thread blocks (4 waves x 16 q-rows = 64 q rows/group). Causal pairing: block p
// handles q-groups p and 31-p (uniform 33 kv-tiles/block). K row-major + Vt (dim-major)
// staged in LDS via global_load_lds with pre-swizzled source; reads XOR-swizzled.
__global__ __launch_bounds__(256) void attn_kernel(const unsigned short* __restrict__ qkv,
                                                   const unsigned short* __restrict__ vtg,
                                                   unsigned short* __restrict__ ctx){
    __shared__ unsigned short Ks[2][4096];
    __shared__ unsigned short Vs[2][4096];
    const int pair = blockIdx.x, bh = blockIdx.y;
    const int b = bh >> 4, h = bh & 15;
    const int tid = threadIdx.x, lane = tid & 63, w = tid >> 6;
    const int lm = lane & 15, g = lane >> 4;
    const long qkvb = (long)b * SEQ * 3072;
    const unsigned short* kglob = qkv + qkvb + 1024 + h*64;     // K rows, stride 3072
    const unsigned short* vglob = vtg + (long)bh * 64 * 2048;   // Vt rows, stride 2048

    const int srow = tid >> 3;          // 0..31
    const int soff = (tid & 7) * 16;    // byte offset in 128B LDS row, pre-swizzle
    f32x4 zero = {0.0f, 0.0f, 0.0f, 0.0f};

    #pragma unroll 1
    for (int grp = 0; grp < 2; ++grp){
        const int qg = (grp == 0) ? pair : (31 - pair);
        const int q0 = qg * 64;
        const int nt = qg + 1;
        const int qrow = q0 + w*16 + lm;

        const unsigned short* qrp = qkv + qkvb + (long)qrow*3072 + h*64;
        const s16x8 qf0 = *(const s16x8*)(qrp + g*8);
        const s16x8 qf1 = *(const s16x8*)(qrp + 32 + g*8);

        f32x4 o[4];
        #pragma unroll
        for (int d = 0; d < 4; ++d) o[d] = zero;
        float mrun = -3e38f, lrun = 0.0f;

        auto stage = [&](int t, int bu){
            const int kv0 = t * 64;
            #pragma unroll
            for (int hh = 0; hh < 2; ++hh){
                const int row = srow + hh*32;
                const int sw  = soff ^ ((row & 7) << 4);
                gload16(kglob + (long)(kv0 + row)*3072 + (sw >> 1),
                        (char*)&Ks[bu][0] + hh*4096 + w*1024);
                gload16(vglob + (long)row*2048 + kv0 + (sw >> 1),
                        (char*)&Vs[bu][0] + hh*4096 + w*1024);
            }
        };

        __syncthreads();                 // protect LDS reuse across groups
        stage(0, 0);
        int cur = 0;
        #pragma unroll 1
        for (int t = 0; t < nt; ++t){
            __syncthreads();             // drains vmcnt: buf[cur] ready
            if (t + 1 < nt) stage(t + 1, cur ^ 1);

            // --- QK^T: S^T tile (64 kv x 16 q) ---
            const char* Kb = (const char*)&Ks[cur][0];
            const int sw = (lm & 7) << 4;
            f32x4 sc[4];
            #pragma unroll
            for (int s = 0; s < 4; ++s){
                const char* rp = Kb + (s*16 + lm)*128;
                s16x8 kf0 = *(const s16x8*)(rp + ((g*16) ^ sw));
                s16x8 kf1 = *(const s16x8*)(rp + ((64 + g*16) ^ sw));
                f32x4 a = mfma16(kf0, qf0, zero);
                sc[s] = mfma16(kf1, qf1, a);
            }

            // --- online softmax (per q-col = lm; kv spread over (s,r,g)) ---
            const bool diag = (t == nt - 1);
            float p[4][4];
            float mx = -3e38f;
            #pragma unroll
            for (int s = 0; s < 4; ++s)
                #pragma unroll
                for (int r = 0; r < 4; ++r){
                    float vv = sc[s][r] * 0.125f;
                    if (diag && (s*16 + 4*g + r > w*16 + lm)) vv = -3e38f;
                    p[s][r] = vv;
                    mx = fmaxf(mx, vv);
                }
            mx = fmaxf(mx, __shfl_xor(mx, 16, 64));
            mx = fmaxf(mx, __shfl_xor(mx, 32, 64));
            const float mnew = fmaxf(mrun, mx);
            const float corr = __expf(mrun - mnew);
            float rs = 0.0f;
            #pragma unroll
            for (int s = 0; s < 4; ++s)
                #pragma unroll
                for (int r = 0; r < 4; ++r){
                    const float e = __expf(p[s][r] - mnew);
                    p[s][r] = e;
                    rs += e;
                }
            rs += __shfl_xor(rs, 16, 64);
            rs += __shfl_xor(rs, 32, 64);
            lrun = lrun * corr + rs;
            mrun = mnew;
            #pragma unroll
            for (int d = 0; d < 4; ++d) o[d] *= corr;

            s16x8 pf0, pf1;
            #pragma unroll
            for (int e = 0; e < 8; ++e){
                pf0[e] = (short)f2bf(p[(e>>2)][e&3]);
                pf1[e] = (short)f2bf(p[2 + (e>>2)][e&3]);
            }

            // --- PV: o[d] += V^T-frag x P-frag ---
            const char* Vb = (const char*)&Vs[cur][0];
            #pragma unroll
            for (int d = 0; d < 4; ++d){
                const char* vrp = Vb + (d*16 + lm)*128;
                s16x4 a0 = *(const s16x4*)(vrp + ((g*8) ^ sw));
                s16x4 a1 = *(const s16x4*)(vrp + ((32 + g*8) ^ sw));
                o[d] = mfma16(cat8(a0, a1), pf0, o[d]);
                s16x4 b0 = *(const s16x4*)(vrp + ((64 + g*8) ^ sw));
                s16x4 b1 = *(const s16x4*)(vrp + ((96 + g*8) ^ sw));
                o[d] = mfma16(cat8(b0, b1), pf1, o[d]);
            }
            cur ^= 1;
        }

        const float inv = 1.0f / lrun;
        unsigned short* cw = ctx + (long)(b*SEQ + qrow)*EMB + h*DH + 4*g;
        #pragma unroll
        for (int d = 0; d < 4; ++d){
            u16x4 ov;
            ov[0] = f2bf(o[d][0]*inv); ov[1] = f2bf(o[d][1]*inv);
            ov[2] = f2bf(o[d][2]*inv); ov[3] = f2bf(o[d][3]*inv);
            *(u16x4*)(cw + d*16) = ov;
        }
    }
}

// ---------------- launch ----------------
extern "C" void kernel_launch(void* const* d_in, const int* in_sizes, int n_in,
                              void* d_out, int out_size, void* d_ws, size_t ws_size,
                              hipStream_t stream){
    const float* x     = (const float*)d_in[0];
    const float* ln1_w = (const float*)d_in[1];
    const float* ln1_b = (const float*)d_in[2];
    const float* w_qkv = (const float*)d_in[3];
    const float* w_ap  = (const float*)d_in[4];
    const float* b_ap  = (const float*)d_in[5];
    const float* ln2_w = (const float*)d_in[6];
    const float* ln2_b = (const float*)d_in[7];
    const float* w_fc  = (const float*)d_in[8];
    const float* b_fc  = (const float*)d_in[9];
    const float* w_pr  = (const float*)d_in[10];
    const float* b_pr  = (const float*)d_in[11];
    float* out = (float*)d_out;

    char* ws = (char*)d_ws;
    unsigned short* wqkvT = (unsigned short*)(ws + 0);          // [3072][1024]
    unsigned short* wapT  = (unsigned short*)(ws + 6291456);    // [1024][1024]
    unsigned short* wfcT  = (unsigned short*)(ws + 8388608);    // [4096][1024]
    unsigned short* wprT  = (unsigned short*)(ws + 16777216);   // [1024][4096]
    unsigned short* h1    = (unsigned short*)(ws + 25165824);   // [4096][1024] (reused as vtg)
    unsigned short* vtg   = (unsigned short*)(ws + 25165824);   // [32][64][2048] after QKV GEMM
    unsigned short* qkv   = (unsigned short*)(ws + 33554432);   // [4096][3072]
    unsigned short* ctx   = (unsigned short*)(ws + 58720256);   // [4096][1024]
    float*          x1    = (float*)(ws + 67108864);            // [4096][1024]
    unsigned short* h2    = (unsigned short*)(ws + 83886080);   // [4096][1024]
    unsigned short* afc   = (unsigned short*)(ws + 92274688);   // [4096][4096]

    dim3 b32(32, 8, 1);
    convT_kernel<<<dim3(3072/32, 1024/32), b32, 0, stream>>>(w_qkv, wqkvT, 1024, 3072);
    convT_kernel<<<dim3(1024/32, 1024/32), b32, 0, stream>>>(w_ap,  wapT,  1024, 1024);
    convT_kernel<<<dim3(4096/32, 1024/32), b32, 0, stream>>>(w_fc,  wfcT,  1024, 4096);
    convT_kernel<<<dim3(1024/32, 4096/32), b32, 0, stream>>>(w_pr,  wprT,  4096, 1024);

    ln_kernel<<<NTOK, 256, 0, stream>>>(x, ln1_w, ln1_b, h1);

    gemm_kernel<0,128,128><<<dim3(3072/128, NTOK/128), 256, 0, stream>>>(
        h1, wqkvT, nullptr, nullptr, qkv, NTOK, 3072, 1024);

    vT_kernel<<<dim3(SEQ/64, 32), 256, 0, stream>>>(qkv, vtg);

    attn_kernel<<<dim3(16, 32), 256, 0, stream>>>(qkv, vtg, ctx);

    gemm_kernel<1,128,64><<<dim3(1024/64, NTOK/128), 256, 0, stream>>>(
        ctx, wapT, b_ap, x, x1, NTOK, 1024, 1024);

    ln_kernel<<<NTOK, 256, 0, stream>>>(x1, ln2_w, ln2_b, h2);

    gemm_kernel<2,128,128><<<dim3(4096/128, NTOK/128), 256, 0, stream>>>(
        h2, wfcT, b_fc, nullptr, afc, NTOK, 4096, 1024);

    gemm_kernel<1,128,64><<<dim3(1024/64, NTOK/128), 256, 0, stream>>>(
        afc, wprT, b_pr, x1, out, NTOK, 1024, 4096);
}